// Round 1
// baseline (103.016 us; speedup 1.0000x reference)
//
#include <hip/hip_runtime.h>

// Fused: h = emb[:, :256] @ W_enc + b_enc ; LayerNorm(h)*gamma+beta ; ReLU
// (topology branch of the reference is a provable no-op: pooled == embeddings)
//
// Round 4: pipeline the K-loop. Round-3 serialized each 32 KB B-chunk load
// behind a vmcnt(0)-draining __syncthreads pair (zero load/compute overlap).
// Now: double-buffered s_b, chunk ch+1 issued BEFORE computing chunk ch,
// single raw s_barrier + explicit vmcnt(0) per chunk (T3 minimal pattern).
// Block grows to 64 rows x 512 threads (8 waves: 2 row-halves x 4 col-quarters)
// -> 256 blocks = 1/CU exactly, half the Wp L2 re-streams, half the per-row
// fixed cost. LDS: 33.3K A + 2x32K B + 2K red ~= 100 KB -> 1 block/CU,
// 2 waves/SIMD (launch_bounds(512,2), VGPR cap 256; acc[2][8]=64 regs static).

typedef unsigned int uint32;
typedef __attribute__((ext_vector_type(8))) short bf16x8;   // 8 bf16 = 4 VGPR
typedef __attribute__((ext_vector_type(4))) float floatx4;  // MFMA C/D

constexpr int D  = 512;   // output width (N)
constexpr int MB = 64;    // rows per block
constexpr int PITCH = 260; // dwords per k8-slice of s_a (256 + 4 stagger)
constexpr float EPS = 1e-5f;

#define AS_G __attribute__((address_space(1)))
#define AS_L __attribute__((address_space(3)))

__device__ inline uint32 pack_bf2(float a, float b) {
    uint32 ua = __float_as_uint(a);
    ua += 0x7FFFu + ((ua >> 16) & 1u);          // RNE
    uint32 ub = __float_as_uint(b);
    ub += 0x7FFFu + ((ub >> 16) & 1u);
    return (ua >> 16) | (ub & 0xFFFF0000u);
}

// W [k=256][n=512] f32 -> Wp bf16, linear index (k8*512 + n)*8 + j  (j = k%8)
__global__ __launch_bounds__(256) void pack_w(const float* __restrict__ W,
                                              uint32* __restrict__ Wp) {
    const int t  = blockIdx.x * 256 + threadIdx.x;   // 0..16383
    const int k8 = t >> 9;                           // 0..31
    const int n  = t & 511;
    uint32 r[4];
    #pragma unroll
    for (int jj = 0; jj < 4; ++jj) {
        float v0 = W[(k8 * 8 + 2 * jj)     * D + n];
        float v1 = W[(k8 * 8 + 2 * jj + 1) * D + n];
        r[jj] = pack_bf2(v0, v1);
    }
    uint4 o; o.x = r[0]; o.y = r[1]; o.z = r[2]; o.w = r[3];
    ((uint4*)Wp)[t] = o;
}

__global__ __launch_bounds__(512, 2)
void topo_mfma(const float* __restrict__ emb,
               const uint32* __restrict__ Wp,
               const float* __restrict__ benc,
               const float* __restrict__ gamma,
               const float* __restrict__ beta,
               float* __restrict__ out)
{
    // A: 32 k8-slices x 64 rows x 16 B, pitch 260 dwords (1040 B: 4-bank stagger)
    __shared__ uint32 s_a[32 * PITCH];          // 33.3 KB
    // B: double-buffered chunk, 4 k8-slices x 512 n x 16 B = 32 KB each, linear
    __shared__ uint32 s_b[2][4 * 512 * 4];      // 64 KB
    __shared__ float2 s_red[4][MB];             // per col-wave row partials (2 KB)

    const int t    = threadIdx.x;
    const int wv   = t >> 6;           // wave 0..7
    const int wr   = wv >> 2;          // row half: rows wr*32 .. wr*32+31
    const int wc   = wv & 3;           // col quarter: cols wc*128 .. wc*128+127
    const int lane = t & 63;
    const int q    = lane >> 4;        // quad 0..3
    const int cl   = lane & 15;
    const long row0 = (long)blockIdx.x * MB;
    const char* gB = (const char*)Wp;

    // ---- issue B chunk 0 (async global->LDS, width 16): 32 x 1 KB slots ----
    #pragma unroll
    for (int i = 0; i < 4; ++i) {
        int sl = wv * 4 + i;
        __builtin_amdgcn_global_load_lds((const AS_G uint32*)(gB + sl * 1024 + lane * 16),
                                         (AS_L uint32*)&s_b[0][sl * 256], 16, 0, 0);
    }

    // ---- stage A: 64 rows x 256 cols f32 -> bf16 [k8][m][8k] ----
    #pragma unroll
    for (int p = 0; p < 4; ++p) {
        int m  = p * 16 + (t >> 5);
        int k8 = t & 31;
        const float4* src = (const float4*)(emb + (row0 + m) * D + k8 * 8);
        float4 f0 = src[0], f1 = src[1];
        uint4 o;
        o.x = pack_bf2(f0.x, f0.y); o.y = pack_bf2(f0.z, f0.w);
        o.z = pack_bf2(f1.x, f1.y); o.w = pack_bf2(f1.z, f1.w);
        *(uint4*)&s_a[k8 * PITCH + m * 4] = o;
    }
    __syncthreads();   // drains A ds_writes AND chunk-0 global_load_lds

    floatx4 acc[2][8];                // 64 regs/lane, ALL indices static
    #pragma unroll
    for (int rt = 0; rt < 2; ++rt)
        #pragma unroll
        for (int n2 = 0; n2 < 8; ++n2)
            acc[rt][n2] = (floatx4){0.f, 0.f, 0.f, 0.f};

    // ---- pipelined K loop: 8 chunks of k=32, double-buffered B ----
    // Per chunk: issue next chunk's loads FIRST (latency hides under compute),
    // then ds_read frags + 16 MFMA, then vmcnt(0) + one raw barrier.
    for (int ch = 0; ch < 8; ++ch) {
        const int cur = ch & 1;
        if (ch < 7) {
            const char* g = gB + (ch + 1) * 32768;
            #pragma unroll
            for (int i = 0; i < 4; ++i) {
                int sl = wv * 4 + i;
                __builtin_amdgcn_global_load_lds((const AS_G uint32*)(g + sl * 1024 + lane * 16),
                                                 (AS_L uint32*)&s_b[cur ^ 1][sl * 256], 16, 0, 0);
            }
        }
        // A frags: lane holds A[m = wr*32 + rt*16 + cl][k = q*8+j]
        const uint32* sa = &s_a[(ch * 4 + q) * PITCH];
        bf16x8 af0 = *(const bf16x8*)&sa[(wr * 32 + cl) * 4];
        bf16x8 af1 = *(const bf16x8*)&sa[(wr * 32 + 16 + cl) * 4];
        const uint32* sb = &s_b[cur][(q * 512 + wc * 128 + cl) * 4];
        #pragma unroll
        for (int n2 = 0; n2 < 8; ++n2) {
            // B frag: lane holds B[k = q*8+j][n = wc*128 + n2*16 + cl]
            bf16x8 bf = *(const bf16x8*)&sb[n2 * 64];
            acc[0][n2] = __builtin_amdgcn_mfma_f32_16x16x32_bf16(af0, bf, acc[0][n2], 0, 0, 0);
            acc[1][n2] = __builtin_amdgcn_mfma_f32_16x16x32_bf16(af1, bf, acc[1][n2], 0, 0, 0);
        }
        // Drain the loads we issued THIS iteration (~compute-phase old), then
        // barrier: next buffer is ready AND all waves are done reading cur.
        asm volatile("s_waitcnt vmcnt(0)" ::: "memory");
        __builtin_amdgcn_s_barrier();
    }

    // ---- epilogue: bias + cross-wave LayerNorm + ReLU ----
    // C/D layout: col = wc*128 + n2*16 + cl, row = wr*32 + rt*16 + q*4 + reg
    float bv[8], sum[2][4], sq[2][4];
    #pragma unroll
    for (int n2 = 0; n2 < 8; ++n2) bv[n2] = benc[wc * 128 + n2 * 16 + cl];
    #pragma unroll
    for (int rt = 0; rt < 2; ++rt)
        #pragma unroll
        for (int r = 0; r < 4; ++r) { sum[rt][r] = 0.f; sq[rt][r] = 0.f; }

    #pragma unroll
    for (int n2 = 0; n2 < 8; ++n2)
        #pragma unroll
        for (int rt = 0; rt < 2; ++rt)
            #pragma unroll
            for (int r = 0; r < 4; ++r) {
                float v = acc[rt][n2][r] + bv[n2];
                acc[rt][n2][r] = v;
                sum[rt][r] += v;
                sq[rt][r] = fmaf(v, v, sq[rt][r]);
            }
    // reduce across the 16 cl-lanes (xor 1,2,4,8 stays within the quad group)
    #pragma unroll
    for (int m = 1; m < 16; m <<= 1)
        #pragma unroll
        for (int rt = 0; rt < 2; ++rt)
            #pragma unroll
            for (int r = 0; r < 4; ++r) {
                sum[rt][r] += __shfl_xor(sum[rt][r], m, 64);
                sq[rt][r]  += __shfl_xor(sq[rt][r],  m, 64);
            }
    if (cl == 0) {
        #pragma unroll
        for (int rt = 0; rt < 2; ++rt)
            #pragma unroll
            for (int r = 0; r < 4; ++r)
                s_red[wc][wr * 32 + rt * 16 + q * 4 + r] = make_float2(sum[rt][r], sq[rt][r]);
    }
    __syncthreads();

    float mu[2][4], inv[2][4];
    #pragma unroll
    for (int rt = 0; rt < 2; ++rt)
        #pragma unroll
        for (int r = 0; r < 4; ++r) {
            int row = wr * 32 + rt * 16 + q * 4 + r;
            float s = 0.f, ss = 0.f;
            #pragma unroll
            for (int w = 0; w < 4; ++w) {
                float2 v = s_red[w][row];
                s += v.x; ss += v.y;
            }
            float m_ = s * (1.f / 512.f);
            float var = ss * (1.f / 512.f) - m_ * m_;
            mu[rt][r] = m_;
            inv[rt][r] = rsqrtf(var + EPS);
        }

    #pragma unroll
    for (int n2 = 0; n2 < 8; ++n2) {
        int c = wc * 128 + n2 * 16 + cl;
        float g = gamma[c], be = beta[c];
        #pragma unroll
        for (int rt = 0; rt < 2; ++rt) {
            float* op = out + (row0 + wr * 32 + rt * 16 + q * 4) * D + c;
            #pragma unroll
            for (int r = 0; r < 4; ++r) {
                float v = (acc[rt][n2][r] - mu[rt][r]) * inv[rt][r] * g + be;
                op[r * D] = fmaxf(v, 0.f);
            }
        }
    }
}

extern "C" void kernel_launch(void* const* d_in, const int* in_sizes, int n_in,
                              void* d_out, int out_size, void* d_ws, size_t ws_size,
                              hipStream_t stream) {
    // inputs: embeddings, W_proj, b_proj, W_enc, b_enc, ln_gamma, ln_beta
    const float* emb   = (const float*)d_in[0];
    const float* Wenc  = (const float*)d_in[3];
    const float* benc  = (const float*)d_in[4];
    const float* gamma = (const float*)d_in[5];
    const float* beta  = (const float*)d_in[6];
    float* outp = (float*)d_out;
    uint32* Wp = (uint32*)d_ws;            // 256 KB packed bf16 W

    pack_w<<<64, 256, 0, stream>>>(Wenc, Wp);
    const int rows = in_sizes[0] / D;      // 16384
    topo_mfma<<<rows / MB, 512, 0, stream>>>(emb, Wp, benc, gamma, beta, outp);
}